// Round 1
// baseline (7546.376 us; speedup 1.0000x reference)
//
#include <hip/hip_runtime.h>
#include <stdint.h>

#define BATCH 4
#define NPTS  8192
#define CFEAT 64
#define MCENT 2048
#define NCENT (BATCH * MCENT)
#define KMAX  64
#define NEGV  -1e30f

// Exact-rounding squared distance, matching numpy's ((dx*dx+dy*dy)+dz*dz)
// with NO fma contraction (discrete neighbor selection requires bit parity).
__device__ __forceinline__ float dist2(float ax, float ay, float az,
                                       float bx, float by, float bz) {
    float dx = __fsub_rn(ax, bx);
    float dy = __fsub_rn(ay, by);
    float dz = __fsub_rn(az, bz);
    return __fadd_rn(__fadd_rn(__fmul_rn(dx, dx), __fmul_rn(dy, dy)),
                     __fmul_rn(dz, dz));
}

__device__ __forceinline__ unsigned long long umin64(unsigned long long a,
                                                     unsigned long long b) {
    return a < b ? a : b;
}

// ---------------------------------------------------------------------------
// Kernel 1: farthest point sampling. One block per batch, 1024 threads,
// 8 points per thread held in registers. Emits pos_s directly into d_out tail.
// ---------------------------------------------------------------------------
__global__ __launch_bounds__(1024) void fps_kernel(const float* __restrict__ pos,
                                                   float* __restrict__ pos_s) {
    const int b = blockIdx.x;
    const float* pb = pos + b * NPTS * 3;
    const int t = threadIdx.x;

    float px[8], py[8], pz[8], mind[8];
#pragma unroll
    for (int i = 0; i < 8; ++i) {
        int p = t + (i << 10);
        px[i] = pb[3 * p + 0];
        py[i] = pb[3 * p + 1];
        pz[i] = pb[3 * p + 2];
        mind[i] = 1e30f;
    }

    __shared__ float rv[16];
    __shared__ int   ri[16];
    __shared__ int   s_win;

    int last = 0;
    for (int m = 0; m < MCENT; ++m) {
        float lx = pb[3 * last + 0];
        float ly = pb[3 * last + 1];
        float lz = pb[3 * last + 2];
        if (t == 0) {
            float* o = pos_s + (b * MCENT + m) * 3;
            o[0] = lx; o[1] = ly; o[2] = lz;
        }
        if (m + 1 == MCENT) break;   // last update/argmax is discarded by scan

        // update mind and take local argmax (tie -> lowest point index:
        // i ascending == index ascending, strict > keeps the earliest)
        float bv; int bp;
#pragma unroll
        for (int i = 0; i < 8; ++i) {
            float d = dist2(px[i], py[i], pz[i], lx, ly, lz);
            mind[i] = fminf(mind[i], d);
            if (i == 0) { bv = mind[0]; bp = t; }
            else if (mind[i] > bv) { bv = mind[i]; bp = t + (i << 10); }
        }
        // wave64 butterfly argmax, tie -> lowest index
#pragma unroll
        for (int s = 1; s < 64; s <<= 1) {
            float ov = __shfl_xor(bv, s);
            int   op = __shfl_xor(bp, s);
            if (ov > bv || (ov == bv && op < bp)) { bv = ov; bp = op; }
        }
        if ((t & 63) == 0) { rv[t >> 6] = bv; ri[t >> 6] = bp; }
        __syncthreads();
        if (t == 0) {
            float gv = rv[0]; int gp = ri[0];
#pragma unroll
            for (int w = 1; w < 16; ++w)
                if (rv[w] > gv || (rv[w] == gv && ri[w] < gp)) { gv = rv[w]; gp = ri[w]; }
            s_win = gp;
        }
        __syncthreads();
        last = s_win;
    }
}

// ---------------------------------------------------------------------------
// Kernel 2: per centroid, the <=64 nearest points with d2 <= 0.16 (scale-2
// ball). Out-of-ball members of top-k are always masked in the reference, so
// they are never needed. Stable order (d2 asc, index asc) via packed u64 keys
// == lax.top_k tie-breaking. 256 threads/block, 32 points/thread in regs,
// 64 rounds of block-wide min-extraction.
// ---------------------------------------------------------------------------
__global__ __launch_bounds__(256) void knn_kernel(const float* __restrict__ pos,
                                                  const float* __restrict__ pos_s,
                                                  int* __restrict__ nidx,
                                                  float* __restrict__ nd2,
                                                  int* __restrict__ ncnt) {
    const int c = blockIdx.x;
    const int b = c >> 11;            // c / MCENT
    const float* pb = pos + b * NPTS * 3;
    const int t = threadIdx.x;

    const float cx = pos_s[c * 3 + 0];
    const float cy = pos_s[c * 3 + 1];
    const float cz = pos_s[c * 3 + 2];

    unsigned long long keys[32];
#pragma unroll
    for (int i = 0; i < 32; ++i) {
        int p = t + (i << 8);
        float d2 = dist2(cx, cy, cz, pb[3 * p + 0], pb[3 * p + 1], pb[3 * p + 2]);
        unsigned long long kk =
            ((unsigned long long)__float_as_uint(d2) << 32) | (unsigned int)p;
        keys[i] = (d2 <= 0.16f) ? kk : ~0ULL;
    }
    unsigned long long lmin = keys[0];
#pragma unroll
    for (int i = 1; i < 32; ++i) lmin = umin64(lmin, keys[i]);

    __shared__ unsigned long long wmin[4];
    __shared__ unsigned long long g_s;

    int cnt = KMAX;
    for (int r = 0; r < KMAX; ++r) {
        unsigned long long v = lmin;
#pragma unroll
        for (int s = 1; s < 64; s <<= 1) {
            unsigned int lo = (unsigned int)v;
            unsigned int hi = (unsigned int)(v >> 32);
            lo = __shfl_xor(lo, s);
            hi = __shfl_xor(hi, s);
            unsigned long long o = ((unsigned long long)hi << 32) | lo;
            v = umin64(v, o);
        }
        if ((t & 63) == 0) wmin[t >> 6] = v;
        __syncthreads();
        if (t == 0) g_s = umin64(umin64(wmin[0], wmin[1]), umin64(wmin[2], wmin[3]));
        __syncthreads();
        unsigned long long g = g_s;
        if (g == ~0ULL) { cnt = r; break; }   // uniform exit
        if (t == 0) {
            nidx[c * KMAX + r] = (int)(g & 0xffffffffULL);
            nd2[c * KMAX + r]  = __uint_as_float((unsigned int)(g >> 32));
        }
        if (lmin == g) {                       // unique owner (keys unique)
#pragma unroll
            for (int i = 0; i < 32; ++i)
                if (keys[i] == g) keys[i] = ~0ULL;
            lmin = keys[0];
#pragma unroll
            for (int i = 1; i < 32; ++i) lmin = umin64(lmin, keys[i]);
        }
        __syncthreads();
    }
    if (t == 0) ncnt[c] = cnt;
}

// ---------------------------------------------------------------------------
// Kernel 3: fused gather + 2-layer MLP + masked max per centroid.
// K neighbors, C1/C2 hidden dims, OUTOFF column offset in the 384-wide output.
// fp32 (tolerance 8e-2 >> fp32 error). One block (256 thr) per centroid.
// ---------------------------------------------------------------------------
template <int K, int C1, int C2, int OUTOFF>
__global__ __launch_bounds__(256) void mlp_kernel(
        const float* __restrict__ x, const float* __restrict__ pos,
        const float* __restrict__ pos_s,
        const int* __restrict__ nidx, const float* __restrict__ nd2,
        const int* __restrict__ ncnt,
        const float* __restrict__ W1, const float* __restrict__ B1,
        const float* __restrict__ W2, const float* __restrict__ B2,
        float* __restrict__ out, float r2) {
    const int c = blockIdx.x;
    const int b = c >> 11;
    const int t = threadIdx.x;

    __shared__ float F[K][68];      // [K][67] padded to 17 float4
    __shared__ float H[K][C1];
    __shared__ int   s_nbr[K];
    __shared__ int   s_valid[K];
    __shared__ float s_ctr[3];

    const int cntAll = ncnt[c];
    const int cnt = cntAll < K ? cntAll : K;
    if (t < 3) s_ctr[t] = pos_s[c * 3 + t];
    if (t < K) {
        bool ok = t < cnt;
        s_nbr[t]   = ok ? nidx[c * KMAX + t] : 0;
        s_valid[t] = ok && (nd2[c * KMAX + t] <= r2);
    }
    __syncthreads();

    // gather features: F[k] = [ x[nbr] (64) | pos[nbr]-ctr (3) | 0 pad ]
    for (int e = t; e < K * 17; e += 256) {
        int k = e / 17, q = e % 17;
        int nbr = s_nbr[k];
        bool ok = k < cnt;
        float4 val;
        if (q < 16) {
            const float4* xr = (const float4*)(x + (b * NPTS + nbr) * CFEAT);
            if (ok) val = xr[q];
            else { val.x = 0.f; val.y = 0.f; val.z = 0.f; val.w = 0.f; }
        } else {
            const float* pp = pos + (b * NPTS + nbr) * 3;
            val.x = ok ? pp[0] - s_ctr[0] : 0.f;
            val.y = ok ? pp[1] - s_ctr[1] : 0.f;
            val.z = ok ? pp[2] - s_ctr[2] : 0.f;
            val.w = 0.f;
        }
        ((float4*)&F[k][0])[q] = val;
    }
    __syncthreads();

    // layer 1: H[k][j] = relu(B1[j] + F[k]·W1[:,j]); W1 column in registers,
    // F rows are wave-uniform LDS float4 broadcasts.
    {
        constexpr int STR = 256 / C1;
        const int j  = t % C1;
        const int kb = t / C1;
        float w1c[68];
#pragma unroll
        for (int i = 0; i < 67; ++i) w1c[i] = W1[i * C1 + j];
        w1c[67] = 0.f;
        const float bj = B1[j];
        for (int k = kb; k < K; k += STR) {
            float acc = bj;
            const float4* fr = (const float4*)&F[k][0];
#pragma unroll
            for (int q = 0; q < 17; ++q) {
                float4 f = fr[q];
                acc = fmaf(f.x, w1c[4 * q + 0], acc);
                acc = fmaf(f.y, w1c[4 * q + 1], acc);
                acc = fmaf(f.z, w1c[4 * q + 2], acc);
                acc = fmaf(f.w, w1c[4 * q + 3], acc);
            }
            H[k][j] = fmaxf(acc, 0.f);
        }
    }
    __syncthreads();

    // layer 2 + masked max over neighbors
    if constexpr (C2 == 256) {
        const int j2 = t;
        float w2c[C1];
#pragma unroll
        for (int i = 0; i < C1; ++i) w2c[i] = W2[i * C2 + j2];
        const float bj = B2[j2];
        float omax = NEGV;
        for (int k = 0; k < K; ++k) {
            if (!s_valid[k]) continue;          // uniform branch
            float acc = bj;
            const float4* hr = (const float4*)&H[k][0];
#pragma unroll
            for (int q = 0; q < C1 / 4; ++q) {
                float4 h = hr[q];
                acc = fmaf(h.x, w2c[4 * q + 0], acc);
                acc = fmaf(h.y, w2c[4 * q + 1], acc);
                acc = fmaf(h.z, w2c[4 * q + 2], acc);
                acc = fmaf(h.w, w2c[4 * q + 3], acc);
            }
            omax = fmaxf(omax, fmaxf(acc, 0.f));
        }
        out[c * 384 + OUTOFF + j2] = omax;
    } else {
        // C2 == 128: 2 thread-groups split the k range, combine via LDS
        const int j2 = t % C2;
        const int g  = t / C2;
        __shared__ float pm[256];
        float w2c[C1];
#pragma unroll
        for (int i = 0; i < C1; ++i) w2c[i] = W2[i * C2 + j2];
        const float bj = B2[j2];
        float omax = NEGV;
        for (int k = g; k < K; k += 2) {
            if (!s_valid[k]) continue;
            float acc = bj;
            const float4* hr = (const float4*)&H[k][0];
#pragma unroll
            for (int q = 0; q < C1 / 4; ++q) {
                float4 h = hr[q];
                acc = fmaf(h.x, w2c[4 * q + 0], acc);
                acc = fmaf(h.y, w2c[4 * q + 1], acc);
                acc = fmaf(h.z, w2c[4 * q + 2], acc);
                acc = fmaf(h.w, w2c[4 * q + 3], acc);
            }
            omax = fmaxf(omax, fmaxf(acc, 0.f));
        }
        pm[t] = omax;
        __syncthreads();
        if (t < C2) out[c * 384 + OUTOFF + t] = fmaxf(pm[t], pm[t + C2]);
    }
}

extern "C" void kernel_launch(void* const* d_in, const int* in_sizes, int n_in,
                              void* d_out, int out_size, void* d_ws, size_t ws_size,
                              hipStream_t stream) {
    const float* x    = (const float*)d_in[0];
    const float* pos  = (const float*)d_in[1];
    const float* w1_0 = (const float*)d_in[2];
    const float* b1_0 = (const float*)d_in[3];
    const float* w1_1 = (const float*)d_in[4];
    const float* b1_1 = (const float*)d_in[5];
    const float* w2_0 = (const float*)d_in[6];
    const float* b2_0 = (const float*)d_in[7];
    const float* w2_1 = (const float*)d_in[8];
    const float* b2_1 = (const float*)d_in[9];

    float* out   = (float*)d_out;
    float* pos_s = out + NCENT * 384;          // second output, written by FPS

    char* ws = (char*)d_ws;
    int*   ncnt = (int*)ws;                                   // NCENT ints
    int*   nidx = (int*)(ws + NCENT * 4);                     // NCENT*64 ints
    float* nd2  = (float*)(ws + NCENT * 4 + NCENT * KMAX * 4);// NCENT*64 floats

    fps_kernel<<<BATCH, 1024, 0, stream>>>(pos, pos_s);
    knn_kernel<<<NCENT, 256, 0, stream>>>(pos, pos_s, nidx, nd2, ncnt);
    mlp_kernel<32, 64, 128, 0><<<NCENT, 256, 0, stream>>>(
        x, pos, pos_s, nidx, nd2, ncnt, w1_0, b1_0, w1_1, b1_1, out, 0.04f);
    mlp_kernel<64, 128, 256, 128><<<NCENT, 256, 0, stream>>>(
        x, pos, pos_s, nidx, nd2, ncnt, w2_0, b2_0, w2_1, b2_1, out, 0.16f);
}

// Round 2
// 4106.668 us; speedup vs baseline: 1.8376x; 1.8376x over previous
//
#include <hip/hip_runtime.h>
#include <stdint.h>

#define BATCH 4
#define NPTS  8192
#define CFEAT 64
#define MCENT 2048
#define NCENT (BATCH * MCENT)
#define KMAX  64
#define NEGV  -1e30f

// Exact-rounding squared distance, matching numpy's ((dx*dx+dy*dy)+dz*dz)
// with NO fma contraction (discrete neighbor selection requires bit parity).
__device__ __forceinline__ float dist2(float ax, float ay, float az,
                                       float bx, float by, float bz) {
    float dx = __fsub_rn(ax, bx);
    float dy = __fsub_rn(ay, by);
    float dz = __fsub_rn(az, bz);
    return __fadd_rn(__fadd_rn(__fmul_rn(dx, dx), __fmul_rn(dy, dy)),
                     __fmul_rn(dz, dz));
}

// DPP lane-permute helpers (VALU-latency cross-lane, vs ds_bpermute ~120cyc)
template <int CTRL>
__device__ __forceinline__ float dppf(float v) {
    return __int_as_float(__builtin_amdgcn_update_dpp(
        __float_as_int(v), __float_as_int(v), CTRL, 0xF, 0xF, false));
}
template <int CTRL>
__device__ __forceinline__ int dppi(int v) {
    return __builtin_amdgcn_update_dpp(v, v, CTRL, 0xF, 0xF, false);
}

// ---------------------------------------------------------------------------
// Kernel 1: farthest point sampling. One block per batch, 256 threads
// (1 wave per SIMD), 32 points per thread in registers. Wave argmax via DPP
// (combine is idempotent: max with tie->lowest index, so bcast steps that
// leave rows unchanged are safe). One barrier/iter, parity double-buffered
// cross-wave slots. Winner coords re-read from L2-resident pos.
// ---------------------------------------------------------------------------
__global__ __launch_bounds__(256) void fps_kernel(const float* __restrict__ pos,
                                                  float* __restrict__ pos_s) {
    const int b = blockIdx.x;
    const float* pb = pos + b * NPTS * 3;
    const int t = threadIdx.x;          // 0..255
    const int w = t >> 6;               // wave id 0..3

    float px[32], py[32], pz[32], mind[32];
#pragma unroll
    for (int i = 0; i < 32; ++i) {
        int p = (i << 8) + t;
        px[i] = pb[3 * p + 0];
        py[i] = pb[3 * p + 1];
        pz[i] = pb[3 * p + 2];
        mind[i] = 1e30f;
    }

    __shared__ float s_bv[2][4];
    __shared__ int   s_bp[2][4];

    // last = 0: broadcast-load its coords
    float lx = pb[0], ly = pb[1], lz = pb[2];

    for (int m = 0; m < MCENT; ++m) {
        if (t == 0) {
            float* o = pos_s + (b * MCENT + m) * 3;
            o[0] = lx; o[1] = ly; o[2] = lz;
        }
        if (m + 1 == MCENT) break;      // final argmax discarded by the scan

        // update mind, merged local argmax (i ascending == p ascending;
        // strict > keeps earliest => lowest index on ties)
        float bv = -1.0f; int bp = 0;
#pragma unroll
        for (int i = 0; i < 32; ++i) {
            float d = dist2(px[i], py[i], pz[i], lx, ly, lz);
            float mn = fminf(mind[i], d);
            mind[i] = mn;
            if (mn > bv) { bv = mn; bp = (i << 8) + t; }
        }

        // wave64 argmax via DPP: xor1, xor2, mirror8, mirror16, bcast15/31.
        // Valid result lands in lane 63 of each wave.
#define RSTEP(C_) { float ov = dppf<C_>(bv); int op_ = dppi<C_>(bp);          \
                    bool tk = (ov > bv) || (ov == bv && op_ < bp);            \
                    bv = tk ? ov : bv; bp = tk ? op_ : bp; }
        RSTEP(0xB1)   // quad_perm [1,0,3,2]  : xor 1
        RSTEP(0x4E)   // quad_perm [2,3,0,1]  : xor 2
        RSTEP(0x141)  // row_half_mirror      : xor 4
        RSTEP(0x140)  // row_mirror           : xor 8
        RSTEP(0x142)  // row_bcast15          : rows 1,3 absorb rows 0,2
        RSTEP(0x143)  // row_bcast31          : upper half absorbs lower
#undef RSTEP

        const int par = m & 1;
        if ((t & 63) == 63) { s_bv[par][w] = bv; s_bp[par][w] = bp; }
        __syncthreads();

        // all threads redundantly pick the block winner (broadcast LDS reads)
        float gv = s_bv[par][0]; int gp = s_bp[par][0];
#pragma unroll
        for (int q = 1; q < 4; ++q) {
            float ov = s_bv[par][q]; int op_ = s_bp[par][q];
            bool tk = (ov > gv) || (ov == gv && op_ < gp);
            gv = tk ? ov : gv; gp = tk ? op_ : gp;
        }
        lx = pb[3 * gp + 0];
        ly = pb[3 * gp + 1];
        lz = pb[3 * gp + 2];
    }
}

// ---------------------------------------------------------------------------
// Kernel 2: exact top-64 (by (d2, idx) u64 key) within ball r=0.4 via
// histogram radix-select + O(C^2) exact ranking. Downstream max-aggregation
// is order-invariant, but ranks reproduce lax.top_k order anyway.
// ---------------------------------------------------------------------------
#define KNN_CAP 320

__global__ __launch_bounds__(256) void knn_kernel(const float* __restrict__ pos,
                                                  const float* __restrict__ pos_s,
                                                  int* __restrict__ nidx,
                                                  float* __restrict__ nd2,
                                                  int* __restrict__ ncnt) {
    const int c = blockIdx.x;
    const int b = c >> 11;              // c / MCENT
    const float* pb = pos + b * NPTS * 3;
    const int t = threadIdx.x;

    const float cx = pos_s[c * 3 + 0];
    const float cy = pos_s[c * 3 + 1];
    const float cz = pos_s[c * 3 + 2];

    __shared__ int hist[64];
    __shared__ int s_B64, s_total, s_cnt;
    __shared__ unsigned long long cand[KNN_CAP];

    if (t < 64) hist[t] = 0;
    if (t == 0) s_cnt = 0;
    __syncthreads();

    float d2r[32];
#pragma unroll
    for (int i = 0; i < 32; ++i) {
        int p = (i << 8) + t;
        float d2 = dist2(cx, cy, cz, pb[3 * p + 0], pb[3 * p + 1], pb[3 * p + 2]);
        d2r[i] = d2;
        if (d2 <= 0.16f) {
            int bkt = (int)(d2 * 400.0f);      // monotone; 0.16f*400 < 64
            bkt = bkt > 63 ? 63 : bkt;
            atomicAdd(&hist[bkt], 1);
        }
    }
    __syncthreads();

    if (t == 0) {
        int cum = 0, B = -1;
#pragma unroll
        for (int j = 0; j < 64; ++j) {
            cum += hist[j];
            if (B < 0 && cum >= 64) B = j;
        }
        s_B64 = (B < 0) ? 63 : B;
        s_total = cum;
    }
    __syncthreads();

    const int B64 = s_B64;
#pragma unroll
    for (int i = 0; i < 32; ++i) {
        float d2 = d2r[i];
        if (d2 <= 0.16f) {
            int bkt = (int)(d2 * 400.0f);
            bkt = bkt > 63 ? 63 : bkt;
            if (bkt <= B64) {
                int slot = atomicAdd(&s_cnt, 1);
                if (slot < KNN_CAP) {
                    int p = (i << 8) + t;
                    cand[slot] = ((unsigned long long)__float_as_uint(d2) << 32)
                                 | (unsigned int)p;
                }
            }
        }
    }
    __syncthreads();

    const int C = s_cnt < KNN_CAP ? s_cnt : KNN_CAP;
    // exact rank: candidate set is downward-closed, so candidate rank ==
    // global in-ball rank. Broadcast LDS reads (wave-uniform j).
    for (int tc = t; tc < C; tc += 256) {
        unsigned long long my = cand[tc];
        int rank = 0;
        for (int j = 0; j < C; ++j) rank += (cand[j] < my) ? 1 : 0;
        if (rank < KMAX) {
            nidx[c * KMAX + rank] = (int)(my & 0xffffffffULL);
            nd2[c * KMAX + rank]  = __uint_as_float((unsigned int)(my >> 32));
        }
    }
    if (t == 0) ncnt[c] = s_total < KMAX ? s_total : KMAX;
}

// ---------------------------------------------------------------------------
// Kernel 3: fused gather + 2-layer MLP + masked max per centroid (unchanged).
// ---------------------------------------------------------------------------
template <int K, int C1, int C2, int OUTOFF>
__global__ __launch_bounds__(256) void mlp_kernel(
        const float* __restrict__ x, const float* __restrict__ pos,
        const float* __restrict__ pos_s,
        const int* __restrict__ nidx, const float* __restrict__ nd2,
        const int* __restrict__ ncnt,
        const float* __restrict__ W1, const float* __restrict__ B1,
        const float* __restrict__ W2, const float* __restrict__ B2,
        float* __restrict__ out, float r2) {
    const int c = blockIdx.x;
    const int b = c >> 11;
    const int t = threadIdx.x;

    __shared__ float F[K][68];      // [K][67] padded to 17 float4
    __shared__ float H[K][C1];
    __shared__ int   s_nbr[K];
    __shared__ int   s_valid[K];
    __shared__ float s_ctr[3];

    const int cntAll = ncnt[c];
    const int cnt = cntAll < K ? cntAll : K;
    if (t < 3) s_ctr[t] = pos_s[c * 3 + t];
    if (t < K) {
        bool ok = t < cnt;
        s_nbr[t]   = ok ? nidx[c * KMAX + t] : 0;
        s_valid[t] = ok && (nd2[c * KMAX + t] <= r2);
    }
    __syncthreads();

    // gather features: F[k] = [ x[nbr] (64) | pos[nbr]-ctr (3) | 0 pad ]
    for (int e = t; e < K * 17; e += 256) {
        int k = e / 17, q = e % 17;
        int nbr = s_nbr[k];
        bool ok = k < cnt;
        float4 val;
        if (q < 16) {
            const float4* xr = (const float4*)(x + (b * NPTS + nbr) * CFEAT);
            if (ok) val = xr[q];
            else { val.x = 0.f; val.y = 0.f; val.z = 0.f; val.w = 0.f; }
        } else {
            const float* pp = pos + (b * NPTS + nbr) * 3;
            val.x = ok ? pp[0] - s_ctr[0] : 0.f;
            val.y = ok ? pp[1] - s_ctr[1] : 0.f;
            val.z = ok ? pp[2] - s_ctr[2] : 0.f;
            val.w = 0.f;
        }
        ((float4*)&F[k][0])[q] = val;
    }
    __syncthreads();

    // layer 1: H[k][j] = relu(B1[j] + F[k]·W1[:,j])
    {
        constexpr int STR = 256 / C1;
        const int j  = t % C1;
        const int kb = t / C1;
        float w1c[68];
#pragma unroll
        for (int i = 0; i < 67; ++i) w1c[i] = W1[i * C1 + j];
        w1c[67] = 0.f;
        const float bj = B1[j];
        for (int k = kb; k < K; k += STR) {
            float acc = bj;
            const float4* fr = (const float4*)&F[k][0];
#pragma unroll
            for (int q = 0; q < 17; ++q) {
                float4 f = fr[q];
                acc = fmaf(f.x, w1c[4 * q + 0], acc);
                acc = fmaf(f.y, w1c[4 * q + 1], acc);
                acc = fmaf(f.z, w1c[4 * q + 2], acc);
                acc = fmaf(f.w, w1c[4 * q + 3], acc);
            }
            H[k][j] = fmaxf(acc, 0.f);
        }
    }
    __syncthreads();

    // layer 2 + masked max over neighbors
    if constexpr (C2 == 256) {
        const int j2 = t;
        float w2c[C1];
#pragma unroll
        for (int i = 0; i < C1; ++i) w2c[i] = W2[i * C2 + j2];
        const float bj = B2[j2];
        float omax = NEGV;
        for (int k = 0; k < K; ++k) {
            if (!s_valid[k]) continue;          // uniform branch
            float acc = bj;
            const float4* hr = (const float4*)&H[k][0];
#pragma unroll
            for (int q = 0; q < C1 / 4; ++q) {
                float4 h = hr[q];
                acc = fmaf(h.x, w2c[4 * q + 0], acc);
                acc = fmaf(h.y, w2c[4 * q + 1], acc);
                acc = fmaf(h.z, w2c[4 * q + 2], acc);
                acc = fmaf(h.w, w2c[4 * q + 3], acc);
            }
            omax = fmaxf(omax, fmaxf(acc, 0.f));
        }
        out[c * 384 + OUTOFF + j2] = omax;
    } else {
        // C2 == 128: 2 thread-groups split the k range, combine via LDS
        const int j2 = t % C2;
        const int g  = t / C2;
        __shared__ float pm[256];
        float w2c[C1];
#pragma unroll
        for (int i = 0; i < C1; ++i) w2c[i] = W2[i * C2 + j2];
        const float bj = B2[j2];
        float omax = NEGV;
        for (int k = g; k < K; k += 2) {
            if (!s_valid[k]) continue;
            float acc = bj;
            const float4* hr = (const float4*)&H[k][0];
#pragma unroll
            for (int q = 0; q < C1 / 4; ++q) {
                float4 h = hr[q];
                acc = fmaf(h.x, w2c[4 * q + 0], acc);
                acc = fmaf(h.y, w2c[4 * q + 1], acc);
                acc = fmaf(h.z, w2c[4 * q + 2], acc);
                acc = fmaf(h.w, w2c[4 * q + 3], acc);
            }
            omax = fmaxf(omax, fmaxf(acc, 0.f));
        }
        pm[t] = omax;
        __syncthreads();
        if (t < C2) out[c * 384 + OUTOFF + t] = fmaxf(pm[t], pm[t + C2]);
    }
}

extern "C" void kernel_launch(void* const* d_in, const int* in_sizes, int n_in,
                              void* d_out, int out_size, void* d_ws, size_t ws_size,
                              hipStream_t stream) {
    const float* x    = (const float*)d_in[0];
    const float* pos  = (const float*)d_in[1];
    const float* w1_0 = (const float*)d_in[2];
    const float* b1_0 = (const float*)d_in[3];
    const float* w1_1 = (const float*)d_in[4];
    const float* b1_1 = (const float*)d_in[5];
    const float* w2_0 = (const float*)d_in[6];
    const float* b2_0 = (const float*)d_in[7];
    const float* w2_1 = (const float*)d_in[8];
    const float* b2_1 = (const float*)d_in[9];

    float* out   = (float*)d_out;
    float* pos_s = out + NCENT * 384;          // second output, written by FPS

    char* ws = (char*)d_ws;
    int*   ncnt = (int*)ws;                                   // NCENT ints
    int*   nidx = (int*)(ws + NCENT * 4);                     // NCENT*64 ints
    float* nd2  = (float*)(ws + NCENT * 4 + NCENT * KMAX * 4);// NCENT*64 floats

    fps_kernel<<<BATCH, 256, 0, stream>>>(pos, pos_s);
    knn_kernel<<<NCENT, 256, 0, stream>>>(pos, pos_s, nidx, nd2, ncnt);
    mlp_kernel<32, 64, 128, 0><<<NCENT, 256, 0, stream>>>(
        x, pos, pos_s, nidx, nd2, ncnt, w1_0, b1_0, w1_1, b1_1, out, 0.04f);
    mlp_kernel<64, 128, 256, 128><<<NCENT, 256, 0, stream>>>(
        x, pos, pos_s, nidx, nd2, ncnt, w2_0, b2_0, w2_1, b2_1, out, 0.16f);
}

// Round 3
// 4036.525 us; speedup vs baseline: 1.8695x; 1.0174x over previous
//
#include <hip/hip_runtime.h>
#include <stdint.h>

#define BATCH 4
#define NPTS  8192
#define CFEAT 64
#define MCENT 2048
#define NCENT (BATCH * MCENT)
#define KMAX  64
#define NEGV  -1e30f

// Exact-rounding squared distance, matching numpy's ((dx*dx+dy*dy)+dz*dz)
// with NO fma contraction (discrete neighbor selection requires bit parity).
__device__ __forceinline__ float dist2(float ax, float ay, float az,
                                       float bx, float by, float bz) {
    float dx = __fsub_rn(ax, bx);
    float dy = __fsub_rn(ay, by);
    float dz = __fsub_rn(az, bz);
    return __fadd_rn(__fadd_rn(__fmul_rn(dx, dx), __fmul_rn(dy, dy)),
                     __fmul_rn(dz, dz));
}

// DPP lane-permute helpers (VALU-latency cross-lane, vs ds_bpermute ~120cyc)
template <int CTRL>
__device__ __forceinline__ float dppf(float v) {
    return __int_as_float(__builtin_amdgcn_update_dpp(
        __float_as_int(v), __float_as_int(v), CTRL, 0xF, 0xF, false));
}
template <int CTRL>
__device__ __forceinline__ int dppi(int v) {
    return __builtin_amdgcn_update_dpp(v, v, CTRL, 0xF, 0xF, false);
}

// ---------------------------------------------------------------------------
// Kernel 1: farthest point sampling. One block per batch, 512 threads
// (2 waves/SIMD for latency hiding), 16 points/thread in registers.
// __launch_bounds__(512,2) => VGPR cap 256: the 64-reg point/mind arrays stay
// in registers (round-2 regression: plain (256) capped at 84 VGPR -> scratch
// spill of 128-reg arrays => 2815us). Wave argmax via DPP, one barrier/iter,
// parity double-buffered cross-wave slots, redundant 8-slot scan.
// ---------------------------------------------------------------------------
#define FPS_T   512
#define FPS_PPT 16
#define FPS_W   (FPS_T / 64)

__global__ __launch_bounds__(FPS_T, 2) void fps_kernel(const float* __restrict__ pos,
                                                       float* __restrict__ pos_s) {
    const int b = blockIdx.x;
    const float* pb = pos + b * NPTS * 3;
    const int t = threadIdx.x;          // 0..511
    const int w = t >> 6;               // wave id 0..7

    float px[FPS_PPT], py[FPS_PPT], pz[FPS_PPT], mind[FPS_PPT];
#pragma unroll
    for (int i = 0; i < FPS_PPT; ++i) {
        int p = (i << 9) + t;
        px[i] = pb[3 * p + 0];
        py[i] = pb[3 * p + 1];
        pz[i] = pb[3 * p + 2];
        mind[i] = 1e30f;
    }

    __shared__ float s_bv[2][FPS_W];
    __shared__ int   s_bp[2][FPS_W];

    // last = 0: broadcast-load its coords
    float lx = pb[0], ly = pb[1], lz = pb[2];

    for (int m = 0; m < MCENT; ++m) {
        if (t == 0) {
            float* o = pos_s + (b * MCENT + m) * 3;
            o[0] = lx; o[1] = ly; o[2] = lz;
        }
        if (m + 1 == MCENT) break;      // final argmax discarded by the scan

        // update mind, local argmax tracking 4-bit slot index (inline-const
        // cndmask). i ascending == p ascending; strict > keeps lowest index.
        float bv = -1.0f; int bi = 0;
#pragma unroll
        for (int i = 0; i < FPS_PPT; ++i) {
            float d = dist2(px[i], py[i], pz[i], lx, ly, lz);
            float mn = fminf(mind[i], d);
            mind[i] = mn;
            bool tk = mn > bv;
            bv = tk ? mn : bv;
            bi = tk ? i : bi;
        }
        int bp = (bi << 9) + t;

        // wave64 argmax via DPP (combine idempotent: max, tie->min index)
#define RSTEP(C_) { float ov = dppf<C_>(bv); int op_ = dppi<C_>(bp);          \
                    bool tk = (ov > bv) || (ov == bv && op_ < bp);            \
                    bv = tk ? ov : bv; bp = tk ? op_ : bp; }
        RSTEP(0xB1)   // quad_perm [1,0,3,2]  : xor 1
        RSTEP(0x4E)   // quad_perm [2,3,0,1]  : xor 2
        RSTEP(0x141)  // row_half_mirror      : xor 4
        RSTEP(0x140)  // row_mirror           : xor 8
        RSTEP(0x142)  // row_bcast15          : rows 1,3 absorb rows 0,2
        RSTEP(0x143)  // row_bcast31          : upper half absorbs lower
#undef RSTEP

        const int par = m & 1;
        if ((t & 63) == 63) { s_bv[par][w] = bv; s_bp[par][w] = bp; }
        __syncthreads();

        // all threads redundantly pick the block winner (broadcast LDS reads)
        float gv = s_bv[par][0]; int gp = s_bp[par][0];
#pragma unroll
        for (int q = 1; q < FPS_W; ++q) {
            float ov = s_bv[par][q]; int op_ = s_bp[par][q];
            bool tk = (ov > gv) || (ov == gv && op_ < gp);
            gv = tk ? ov : gv; gp = tk ? op_ : gp;
        }
        lx = pb[3 * gp + 0];
        ly = pb[3 * gp + 1];
        lz = pb[3 * gp + 2];
    }
}

// ---------------------------------------------------------------------------
// Kernel 2: exact top-64 (by (d2, idx) u64 key) within ball r=0.4 via
// histogram radix-select + O(C^2) exact ranking. Downstream max-aggregation
// is order-invariant, but ranks reproduce lax.top_k order anyway.
// ---------------------------------------------------------------------------
#define KNN_CAP 320

__global__ __launch_bounds__(256) void knn_kernel(const float* __restrict__ pos,
                                                  const float* __restrict__ pos_s,
                                                  int* __restrict__ nidx,
                                                  float* __restrict__ nd2,
                                                  int* __restrict__ ncnt) {
    const int c = blockIdx.x;
    const int b = c >> 11;              // c / MCENT
    const float* pb = pos + b * NPTS * 3;
    const int t = threadIdx.x;

    const float cx = pos_s[c * 3 + 0];
    const float cy = pos_s[c * 3 + 1];
    const float cz = pos_s[c * 3 + 2];

    __shared__ int hist[64];
    __shared__ int s_B64, s_total, s_cnt;
    __shared__ unsigned long long cand[KNN_CAP];

    if (t < 64) hist[t] = 0;
    if (t == 0) s_cnt = 0;
    __syncthreads();

    float d2r[32];
#pragma unroll
    for (int i = 0; i < 32; ++i) {
        int p = (i << 8) + t;
        float d2 = dist2(cx, cy, cz, pb[3 * p + 0], pb[3 * p + 1], pb[3 * p + 2]);
        d2r[i] = d2;
        if (d2 <= 0.16f) {
            int bkt = (int)(d2 * 400.0f);      // monotone; 0.16f*400 < 64
            bkt = bkt > 63 ? 63 : bkt;
            atomicAdd(&hist[bkt], 1);
        }
    }
    __syncthreads();

    if (t == 0) {
        int cum = 0, B = -1;
#pragma unroll
        for (int j = 0; j < 64; ++j) {
            cum += hist[j];
            if (B < 0 && cum >= 64) B = j;
        }
        s_B64 = (B < 0) ? 63 : B;
        s_total = cum;
    }
    __syncthreads();

    const int B64 = s_B64;
#pragma unroll
    for (int i = 0; i < 32; ++i) {
        float d2 = d2r[i];
        if (d2 <= 0.16f) {
            int bkt = (int)(d2 * 400.0f);
            bkt = bkt > 63 ? 63 : bkt;
            if (bkt <= B64) {
                int slot = atomicAdd(&s_cnt, 1);
                if (slot < KNN_CAP) {
                    int p = (i << 8) + t;
                    cand[slot] = ((unsigned long long)__float_as_uint(d2) << 32)
                                 | (unsigned int)p;
                }
            }
        }
    }
    __syncthreads();

    const int C = s_cnt < KNN_CAP ? s_cnt : KNN_CAP;
    // exact rank: candidate set is downward-closed, so candidate rank ==
    // global in-ball rank. Broadcast LDS reads (wave-uniform j).
    for (int tc = t; tc < C; tc += 256) {
        unsigned long long my = cand[tc];
        int rank = 0;
        for (int j = 0; j < C; ++j) rank += (cand[j] < my) ? 1 : 0;
        if (rank < KMAX) {
            nidx[c * KMAX + rank] = (int)(my & 0xffffffffULL);
            nd2[c * KMAX + rank]  = __uint_as_float((unsigned int)(my >> 32));
        }
    }
    if (t == 0) ncnt[c] = s_total < KMAX ? s_total : KMAX;
}

// ---------------------------------------------------------------------------
// Kernel 3: fused gather + 2-layer MLP + masked max per centroid.
// __launch_bounds__(256,2): w2c[128] (C1=128 variant) needs 128 VGPRs —
// the plain (256) heuristic risks an 84-VGPR cap + scratch spill (seen on
// fps in round 2). LDS (~50KB for K=64) limits blocks/CU anyway.
// ---------------------------------------------------------------------------
template <int K, int C1, int C2, int OUTOFF>
__global__ __launch_bounds__(256, 2) void mlp_kernel(
        const float* __restrict__ x, const float* __restrict__ pos,
        const float* __restrict__ pos_s,
        const int* __restrict__ nidx, const float* __restrict__ nd2,
        const int* __restrict__ ncnt,
        const float* __restrict__ W1, const float* __restrict__ B1,
        const float* __restrict__ W2, const float* __restrict__ B2,
        float* __restrict__ out, float r2) {
    const int c = blockIdx.x;
    const int b = c >> 11;
    const int t = threadIdx.x;

    __shared__ float F[K][68];      // [K][67] padded to 17 float4
    __shared__ float H[K][C1];
    __shared__ int   s_nbr[K];
    __shared__ int   s_valid[K];
    __shared__ float s_ctr[3];

    const int cntAll = ncnt[c];
    const int cnt = cntAll < K ? cntAll : K;
    if (t < 3) s_ctr[t] = pos_s[c * 3 + t];
    if (t < K) {
        bool ok = t < cnt;
        s_nbr[t]   = ok ? nidx[c * KMAX + t] : 0;
        s_valid[t] = ok && (nd2[c * KMAX + t] <= r2);
    }
    __syncthreads();

    // gather features: F[k] = [ x[nbr] (64) | pos[nbr]-ctr (3) | 0 pad ]
    for (int e = t; e < K * 17; e += 256) {
        int k = e / 17, q = e % 17;
        int nbr = s_nbr[k];
        bool ok = k < cnt;
        float4 val;
        if (q < 16) {
            const float4* xr = (const float4*)(x + (b * NPTS + nbr) * CFEAT);
            if (ok) val = xr[q];
            else { val.x = 0.f; val.y = 0.f; val.z = 0.f; val.w = 0.f; }
        } else {
            const float* pp = pos + (b * NPTS + nbr) * 3;
            val.x = ok ? pp[0] - s_ctr[0] : 0.f;
            val.y = ok ? pp[1] - s_ctr[1] : 0.f;
            val.z = ok ? pp[2] - s_ctr[2] : 0.f;
            val.w = 0.f;
        }
        ((float4*)&F[k][0])[q] = val;
    }
    __syncthreads();

    // layer 1: H[k][j] = relu(B1[j] + F[k]·W1[:,j])
    {
        constexpr int STR = 256 / C1;
        const int j  = t % C1;
        const int kb = t / C1;
        float w1c[68];
#pragma unroll
        for (int i = 0; i < 67; ++i) w1c[i] = W1[i * C1 + j];
        w1c[67] = 0.f;
        const float bj = B1[j];
        for (int k = kb; k < K; k += STR) {
            float acc = bj;
            const float4* fr = (const float4*)&F[k][0];
#pragma unroll
            for (int q = 0; q < 17; ++q) {
                float4 f = fr[q];
                acc = fmaf(f.x, w1c[4 * q + 0], acc);
                acc = fmaf(f.y, w1c[4 * q + 1], acc);
                acc = fmaf(f.z, w1c[4 * q + 2], acc);
                acc = fmaf(f.w, w1c[4 * q + 3], acc);
            }
            H[k][j] = fmaxf(acc, 0.f);
        }
    }
    __syncthreads();

    // layer 2 + masked max over neighbors
    if constexpr (C2 == 256) {
        const int j2 = t;
        float w2c[C1];
#pragma unroll
        for (int i = 0; i < C1; ++i) w2c[i] = W2[i * C2 + j2];
        const float bj = B2[j2];
        float omax = NEGV;
        for (int k = 0; k < K; ++k) {
            if (!s_valid[k]) continue;          // uniform branch
            float acc = bj;
            const float4* hr = (const float4*)&H[k][0];
#pragma unroll
            for (int q = 0; q < C1 / 4; ++q) {
                float4 h = hr[q];
                acc = fmaf(h.x, w2c[4 * q + 0], acc);
                acc = fmaf(h.y, w2c[4 * q + 1], acc);
                acc = fmaf(h.z, w2c[4 * q + 2], acc);
                acc = fmaf(h.w, w2c[4 * q + 3], acc);
            }
            omax = fmaxf(omax, fmaxf(acc, 0.f));
        }
        out[c * 384 + OUTOFF + j2] = omax;
    } else {
        // C2 == 128: 2 thread-groups split the k range, combine via LDS
        const int j2 = t % C2;
        const int g  = t / C2;
        __shared__ float pm[256];
        float w2c[C1];
#pragma unroll
        for (int i = 0; i < C1; ++i) w2c[i] = W2[i * C2 + j2];
        const float bj = B2[j2];
        float omax = NEGV;
        for (int k = g; k < K; k += 2) {
            if (!s_valid[k]) continue;
            float acc = bj;
            const float4* hr = (const float4*)&H[k][0];
#pragma unroll
            for (int q = 0; q < C1 / 4; ++q) {
                float4 h = hr[q];
                acc = fmaf(h.x, w2c[4 * q + 0], acc);
                acc = fmaf(h.y, w2c[4 * q + 1], acc);
                acc = fmaf(h.z, w2c[4 * q + 2], acc);
                acc = fmaf(h.w, w2c[4 * q + 3], acc);
            }
            omax = fmaxf(omax, fmaxf(acc, 0.f));
        }
        pm[t] = omax;
        __syncthreads();
        if (t < C2) out[c * 384 + OUTOFF + t] = fmaxf(pm[t], pm[t + C2]);
    }
}

extern "C" void kernel_launch(void* const* d_in, const int* in_sizes, int n_in,
                              void* d_out, int out_size, void* d_ws, size_t ws_size,
                              hipStream_t stream) {
    const float* x    = (const float*)d_in[0];
    const float* pos  = (const float*)d_in[1];
    const float* w1_0 = (const float*)d_in[2];
    const float* b1_0 = (const float*)d_in[3];
    const float* w1_1 = (const float*)d_in[4];
    const float* b1_1 = (const float*)d_in[5];
    const float* w2_0 = (const float*)d_in[6];
    const float* b2_0 = (const float*)d_in[7];
    const float* w2_1 = (const float*)d_in[8];
    const float* b2_1 = (const float*)d_in[9];

    float* out   = (float*)d_out;
    float* pos_s = out + NCENT * 384;          // second output, written by FPS

    char* ws = (char*)d_ws;
    int*   ncnt = (int*)ws;                                   // NCENT ints
    int*   nidx = (int*)(ws + NCENT * 4);                     // NCENT*64 ints
    float* nd2  = (float*)(ws + NCENT * 4 + NCENT * KMAX * 4);// NCENT*64 floats

    fps_kernel<<<BATCH, FPS_T, 0, stream>>>(pos, pos_s);
    knn_kernel<<<NCENT, 256, 0, stream>>>(pos, pos_s, nidx, nd2, ncnt);
    mlp_kernel<32, 64, 128, 0><<<NCENT, 256, 0, stream>>>(
        x, pos, pos_s, nidx, nd2, ncnt, w1_0, b1_0, w1_1, b1_1, out, 0.04f);
    mlp_kernel<64, 128, 256, 128><<<NCENT, 256, 0, stream>>>(
        x, pos, pos_s, nidx, nd2, ncnt, w2_0, b2_0, w2_1, b2_1, out, 0.16f);
}

// Round 4
// 4036.068 us; speedup vs baseline: 1.8697x; 1.0001x over previous
//
#include <hip/hip_runtime.h>
#include <stdint.h>

#define BATCH 4
#define NPTS  8192
#define CFEAT 64
#define MCENT 2048
#define NCENT (BATCH * MCENT)
#define KMAX  64
#define NEGV  -1e30f

// Exact-rounding squared distance, matching numpy's ((dx*dx+dy*dy)+dz*dz)
// with NO fma contraction (discrete neighbor selection requires bit parity).
__device__ __forceinline__ float dist2(float ax, float ay, float az,
                                       float bx, float by, float bz) {
    float dx = __fsub_rn(ax, bx);
    float dy = __fsub_rn(ay, by);
    float dz = __fsub_rn(az, bz);
    return __fadd_rn(__fadd_rn(__fmul_rn(dx, dx), __fmul_rn(dy, dy)),
                     __fmul_rn(dz, dz));
}

// DPP lane-permute helpers (VALU-latency cross-lane, vs ds_bpermute ~120cyc)
template <int CTRL>
__device__ __forceinline__ float dppf(float v) {
    return __int_as_float(__builtin_amdgcn_update_dpp(
        __float_as_int(v), __float_as_int(v), CTRL, 0xF, 0xF, false));
}
template <int CTRL>
__device__ __forceinline__ int dppi(int v) {
    return __builtin_amdgcn_update_dpp(v, v, CTRL, 0xF, 0xF, false);
}

// ---------------------------------------------------------------------------
// Kernel 1: farthest point sampling. One block per batch, 512 threads
// (2 waves/SIMD), 16 points per thread.
//
// Round-3 post-mortem: private ARRAYS (px[16] etc) were never SROA-promoted
// (loop unroll happens after SROA) -> allocas lowered to SCRATCH, VGPR_Count
// was 48 with ~256B/thread/iter of spill traffic => 2879us. Fix: 64 named
// scalar registers via macro expansion — no alloca can exist, promotion is
// structural, not heuristic.
// ---------------------------------------------------------------------------
#define FPS_T   512
#define FPS_W   (FPS_T / 64)

#define REP16(X) X(0) X(1) X(2) X(3) X(4) X(5) X(6) X(7) \
                 X(8) X(9) X(10) X(11) X(12) X(13) X(14) X(15)

__global__ __launch_bounds__(FPS_T, 2) void fps_kernel(const float* __restrict__ pos,
                                                       float* __restrict__ pos_s) {
    const int b = blockIdx.x;
    const float* pb = pos + b * NPTS * 3;
    const int t = threadIdx.x;          // 0..511
    const int w = t >> 6;               // wave id 0..7

#define FPS_DECL(i) float px##i, py##i, pz##i, mind##i;
    REP16(FPS_DECL)
#undef FPS_DECL

#define FPS_LOAD(i) { int p = (i << 9) + t;            \
                      px##i = pb[3 * p + 0];           \
                      py##i = pb[3 * p + 1];           \
                      pz##i = pb[3 * p + 2];           \
                      mind##i = 1e30f; }
    REP16(FPS_LOAD)
#undef FPS_LOAD

    __shared__ float s_bv[2][FPS_W];
    __shared__ int   s_bp[2][FPS_W];

    // last = 0: broadcast-load its coords
    float lx = pb[0], ly = pb[1], lz = pb[2];

    for (int m = 0; m < MCENT; ++m) {
        if (t == 0) {
            float* o = pos_s + (b * MCENT + m) * 3;
            o[0] = lx; o[1] = ly; o[2] = lz;
        }
        if (m + 1 == MCENT) break;      // final argmax discarded by the scan

        // update mind, local argmax over the 16 slots (i ascending == point
        // index ascending for fixed t; strict > keeps the lowest index).
        float bv = -1.0f; int bi = 0;
#define FPS_UPD(i) { float d = dist2(px##i, py##i, pz##i, lx, ly, lz);        \
                     float mn = fminf(mind##i, d);                            \
                     mind##i = mn;                                            \
                     bool tk = mn > bv;                                       \
                     bv = tk ? mn : bv;                                       \
                     bi = tk ? i : bi; }
        REP16(FPS_UPD)
#undef FPS_UPD
        int bp = (bi << 9) + t;

        // wave64 argmax via DPP (combine idempotent: max, tie->min index)
#define RSTEP(C_) { float ov = dppf<C_>(bv); int op_ = dppi<C_>(bp);          \
                    bool tk = (ov > bv) || (ov == bv && op_ < bp);            \
                    bv = tk ? ov : bv; bp = tk ? op_ : bp; }
        RSTEP(0xB1)   // quad_perm [1,0,3,2]  : xor 1
        RSTEP(0x4E)   // quad_perm [2,3,0,1]  : xor 2
        RSTEP(0x141)  // row_half_mirror      : xor 4
        RSTEP(0x140)  // row_mirror           : xor 8
        RSTEP(0x142)  // row_bcast15          : rows 1,3 absorb rows 0,2
        RSTEP(0x143)  // row_bcast31          : upper half absorbs lower
#undef RSTEP

        const int par = m & 1;
        if ((t & 63) == 63) { s_bv[par][w] = bv; s_bp[par][w] = bp; }
        __syncthreads();

        // all threads redundantly pick the block winner (broadcast LDS reads)
        float gv = s_bv[par][0]; int gp = s_bp[par][0];
#pragma unroll
        for (int q = 1; q < FPS_W; ++q) {
            float ov = s_bv[par][q]; int op_ = s_bp[par][q];
            bool tk = (ov > gv) || (ov == gv && op_ < gp);
            gv = tk ? ov : gv; gp = tk ? op_ : gp;
        }
        lx = pb[3 * gp + 0];
        ly = pb[3 * gp + 1];
        lz = pb[3 * gp + 2];
    }
}

// ---------------------------------------------------------------------------
// Kernel 2: exact top-64 (by (d2, idx) u64 key) within ball r=0.4 via
// histogram radix-select + O(C^2) exact ranking. Downstream max-aggregation
// is order-invariant, but ranks reproduce lax.top_k order anyway.
// ---------------------------------------------------------------------------
#define KNN_CAP 320

__global__ __launch_bounds__(256) void knn_kernel(const float* __restrict__ pos,
                                                  const float* __restrict__ pos_s,
                                                  int* __restrict__ nidx,
                                                  float* __restrict__ nd2,
                                                  int* __restrict__ ncnt) {
    const int c = blockIdx.x;
    const int b = c >> 11;              // c / MCENT
    const float* pb = pos + b * NPTS * 3;
    const int t = threadIdx.x;

    const float cx = pos_s[c * 3 + 0];
    const float cy = pos_s[c * 3 + 1];
    const float cz = pos_s[c * 3 + 2];

    __shared__ int hist[64];
    __shared__ int s_B64, s_total, s_cnt;
    __shared__ unsigned long long cand[KNN_CAP];

    if (t < 64) hist[t] = 0;
    if (t == 0) s_cnt = 0;
    __syncthreads();

    float d2r[32];
#pragma unroll
    for (int i = 0; i < 32; ++i) {
        int p = (i << 8) + t;
        float d2 = dist2(cx, cy, cz, pb[3 * p + 0], pb[3 * p + 1], pb[3 * p + 2]);
        d2r[i] = d2;
        if (d2 <= 0.16f) {
            int bkt = (int)(d2 * 400.0f);      // monotone; 0.16f*400 < 64
            bkt = bkt > 63 ? 63 : bkt;
            atomicAdd(&hist[bkt], 1);
        }
    }
    __syncthreads();

    if (t == 0) {
        int cum = 0, B = -1;
#pragma unroll
        for (int j = 0; j < 64; ++j) {
            cum += hist[j];
            if (B < 0 && cum >= 64) B = j;
        }
        s_B64 = (B < 0) ? 63 : B;
        s_total = cum;
    }
    __syncthreads();

    const int B64 = s_B64;
#pragma unroll
    for (int i = 0; i < 32; ++i) {
        float d2 = d2r[i];
        if (d2 <= 0.16f) {
            int bkt = (int)(d2 * 400.0f);
            bkt = bkt > 63 ? 63 : bkt;
            if (bkt <= B64) {
                int slot = atomicAdd(&s_cnt, 1);
                if (slot < KNN_CAP) {
                    int p = (i << 8) + t;
                    cand[slot] = ((unsigned long long)__float_as_uint(d2) << 32)
                                 | (unsigned int)p;
                }
            }
        }
    }
    __syncthreads();

    const int C = s_cnt < KNN_CAP ? s_cnt : KNN_CAP;
    // exact rank: candidate set is downward-closed, so candidate rank ==
    // global in-ball rank. Broadcast LDS reads (wave-uniform j).
    for (int tc = t; tc < C; tc += 256) {
        unsigned long long my = cand[tc];
        int rank = 0;
        for (int j = 0; j < C; ++j) rank += (cand[j] < my) ? 1 : 0;
        if (rank < KMAX) {
            nidx[c * KMAX + rank] = (int)(my & 0xffffffffULL);
            nd2[c * KMAX + rank]  = __uint_as_float((unsigned int)(my >> 32));
        }
    }
    if (t == 0) ncnt[c] = s_total < KMAX ? s_total : KMAX;
}

// ---------------------------------------------------------------------------
// Kernel 3: fused gather + 2-layer MLP + masked max per centroid.
// ---------------------------------------------------------------------------
template <int K, int C1, int C2, int OUTOFF>
__global__ __launch_bounds__(256, 2) void mlp_kernel(
        const float* __restrict__ x, const float* __restrict__ pos,
        const float* __restrict__ pos_s,
        const int* __restrict__ nidx, const float* __restrict__ nd2,
        const int* __restrict__ ncnt,
        const float* __restrict__ W1, const float* __restrict__ B1,
        const float* __restrict__ W2, const float* __restrict__ B2,
        float* __restrict__ out, float r2) {
    const int c = blockIdx.x;
    const int b = c >> 11;
    const int t = threadIdx.x;

    __shared__ float F[K][68];      // [K][67] padded to 17 float4
    __shared__ float H[K][C1];
    __shared__ int   s_nbr[K];
    __shared__ int   s_valid[K];
    __shared__ float s_ctr[3];

    const int cntAll = ncnt[c];
    const int cnt = cntAll < K ? cntAll : K;
    if (t < 3) s_ctr[t] = pos_s[c * 3 + t];
    if (t < K) {
        bool ok = t < cnt;
        s_nbr[t]   = ok ? nidx[c * KMAX + t] : 0;
        s_valid[t] = ok && (nd2[c * KMAX + t] <= r2);
    }
    __syncthreads();

    // gather features: F[k] = [ x[nbr] (64) | pos[nbr]-ctr (3) | 0 pad ]
    for (int e = t; e < K * 17; e += 256) {
        int k = e / 17, q = e % 17;
        int nbr = s_nbr[k];
        bool ok = k < cnt;
        float4 val;
        if (q < 16) {
            const float4* xr = (const float4*)(x + (b * NPTS + nbr) * CFEAT);
            if (ok) val = xr[q];
            else { val.x = 0.f; val.y = 0.f; val.z = 0.f; val.w = 0.f; }
        } else {
            const float* pp = pos + (b * NPTS + nbr) * 3;
            val.x = ok ? pp[0] - s_ctr[0] : 0.f;
            val.y = ok ? pp[1] - s_ctr[1] : 0.f;
            val.z = ok ? pp[2] - s_ctr[2] : 0.f;
            val.w = 0.f;
        }
        ((float4*)&F[k][0])[q] = val;
    }
    __syncthreads();

    // layer 1: H[k][j] = relu(B1[j] + F[k]·W1[:,j])
    {
        constexpr int STR = 256 / C1;
        const int j  = t % C1;
        const int kb = t / C1;
        float w1c[68];
#pragma unroll
        for (int i = 0; i < 67; ++i) w1c[i] = W1[i * C1 + j];
        w1c[67] = 0.f;
        const float bj = B1[j];
        for (int k = kb; k < K; k += STR) {
            float acc = bj;
            const float4* fr = (const float4*)&F[k][0];
#pragma unroll
            for (int q = 0; q < 17; ++q) {
                float4 f = fr[q];
                acc = fmaf(f.x, w1c[4 * q + 0], acc);
                acc = fmaf(f.y, w1c[4 * q + 1], acc);
                acc = fmaf(f.z, w1c[4 * q + 2], acc);
                acc = fmaf(f.w, w1c[4 * q + 3], acc);
            }
            H[k][j] = fmaxf(acc, 0.f);
        }
    }
    __syncthreads();

    // layer 2 + masked max over neighbors
    if constexpr (C2 == 256) {
        const int j2 = t;
        float w2c[C1];
#pragma unroll
        for (int i = 0; i < C1; ++i) w2c[i] = W2[i * C2 + j2];
        const float bj = B2[j2];
        float omax = NEGV;
        for (int k = 0; k < K; ++k) {
            if (!s_valid[k]) continue;          // uniform branch
            float acc = bj;
            const float4* hr = (const float4*)&H[k][0];
#pragma unroll
            for (int q = 0; q < C1 / 4; ++q) {
                float4 h = hr[q];
                acc = fmaf(h.x, w2c[4 * q + 0], acc);
                acc = fmaf(h.y, w2c[4 * q + 1], acc);
                acc = fmaf(h.z, w2c[4 * q + 2], acc);
                acc = fmaf(h.w, w2c[4 * q + 3], acc);
            }
            omax = fmaxf(omax, fmaxf(acc, 0.f));
        }
        out[c * 384 + OUTOFF + j2] = omax;
    } else {
        // C2 == 128: 2 thread-groups split the k range, combine via LDS
        const int j2 = t % C2;
        const int g  = t / C2;
        __shared__ float pm[256];
        float w2c[C1];
#pragma unroll
        for (int i = 0; i < C1; ++i) w2c[i] = W2[i * C2 + j2];
        const float bj = B2[j2];
        float omax = NEGV;
        for (int k = g; k < K; k += 2) {
            if (!s_valid[k]) continue;
            float acc = bj;
            const float4* hr = (const float4*)&H[k][0];
#pragma unroll
            for (int q = 0; q < C1 / 4; ++q) {
                float4 h = hr[q];
                acc = fmaf(h.x, w2c[4 * q + 0], acc);
                acc = fmaf(h.y, w2c[4 * q + 1], acc);
                acc = fmaf(h.z, w2c[4 * q + 2], acc);
                acc = fmaf(h.w, w2c[4 * q + 3], acc);
            }
            omax = fmaxf(omax, fmaxf(acc, 0.f));
        }
        pm[t] = omax;
        __syncthreads();
        if (t < C2) out[c * 384 + OUTOFF + t] = fmaxf(pm[t], pm[t + C2]);
    }
}

extern "C" void kernel_launch(void* const* d_in, const int* in_sizes, int n_in,
                              void* d_out, int out_size, void* d_ws, size_t ws_size,
                              hipStream_t stream) {
    const float* x    = (const float*)d_in[0];
    const float* pos  = (const float*)d_in[1];
    const float* w1_0 = (const float*)d_in[2];
    const float* b1_0 = (const float*)d_in[3];
    const float* w1_1 = (const float*)d_in[4];
    const float* b1_1 = (const float*)d_in[5];
    const float* w2_0 = (const float*)d_in[6];
    const float* b2_0 = (const float*)d_in[7];
    const float* w2_1 = (const float*)d_in[8];
    const float* b2_1 = (const float*)d_in[9];

    float* out   = (float*)d_out;
    float* pos_s = out + NCENT * 384;          // second output, written by FPS

    char* ws = (char*)d_ws;
    int*   ncnt = (int*)ws;                                   // NCENT ints
    int*   nidx = (int*)(ws + NCENT * 4);                     // NCENT*64 ints
    float* nd2  = (float*)(ws + NCENT * 4 + NCENT * KMAX * 4);// NCENT*64 floats

    fps_kernel<<<BATCH, FPS_T, 0, stream>>>(pos, pos_s);
    knn_kernel<<<NCENT, 256, 0, stream>>>(pos, pos_s, nidx, nd2, ncnt);
    mlp_kernel<32, 64, 128, 0><<<NCENT, 256, 0, stream>>>(
        x, pos, pos_s, nidx, nd2, ncnt, w1_0, b1_0, w1_1, b1_1, out, 0.04f);
    mlp_kernel<64, 128, 256, 128><<<NCENT, 256, 0, stream>>>(
        x, pos, pos_s, nidx, nd2, ncnt, w2_0, b2_0, w2_1, b2_1, out, 0.16f);
}